// Round 9
// baseline (3105.336 us; speedup 1.0000x reference)
//
#include <hip/hip_runtime.h>
#include <hip/hip_cooperative_groups.h>

namespace cg = cooperative_groups;

// 2D acoustic FDTD, persistent cooperative kernel with temporal blocking.
// One launch, NT=600 steps. 32 strips (8 interior rows) x B blocks = 64
// blocks of 512 threads (8 waves = 2/SIMD). Each wave owns 5 consecutive
// rows in NAMED float4 registers; band top/bottom rows exchange via LDS
// ping-pong each step; strips exchange halo via global + grid.sync every
// KT=16 steps. Lateral neighbors via DPP (bound_ctrl = domain edge zeros).
// R9 == R7 resubmit #2 (R7: container failed twice; R8: GPU acquisition
// timeout -- kernel has never actually run).
// R7 vs R6: 16 -> 64 blocks, 4 -> 2 waves/SIMD (R6 was VALU-issue-bound on
// 16 CUs: 1.27us/step with ~1kcyc/SIMD issue time; this quarters per-SIMD
// issue and halves barrier width).

#define HH 256
#define WW 256
#define KT 16                 // time steps per chunk == halo rows
#define SHR 8                 // strip interior height
#define NSTRIP (HH / SHR)     // 32
#define NSLOT 8               // row-slots (= waves) per block
#define RPT 5                 // rows per thread (band height); 8*5=40 >= 8+2*16
#define NTH 512
#define C2SCALE 1.0e-4f       // DT/DX
#define NRMAX 128

__device__ __forceinline__ float dpp_west(float v) {
    // lane i <- lane i-1 ; lane 0 <- 0   (wave_shr:1, bound_ctrl:1)
    return __int_as_float(__builtin_amdgcn_mov_dpp(__float_as_int(v), 0x138, 0xf, 0xf, true));
}
__device__ __forceinline__ float dpp_east(float v) {
    // lane i <- lane i+1 ; lane 63 <- 0  (wave_shl:1, bound_ctrl:1)
    return __int_as_float(__builtin_amdgcn_mov_dpp(__float_as_int(v), 0x130, 0xf, 0xf, true));
}

#define ZERO4 make_float4(0.f, 0.f, 0.f, 0.f)

// P = 2*C - P + CI * lap(N, C, S)     (in-place leapfrog, P aliases u_{t-1})
#define LAPROW(P, NN, CC, SS, CI)                                            \
    {                                                                        \
        const float wl_ = dpp_west((CC).w);                                  \
        const float er_ = dpp_east((CC).x);                                  \
        const float lx_ = (NN).x + (SS).x + wl_    + (CC).y - 4.0f * (CC).x; \
        const float ly_ = (NN).y + (SS).y + (CC).x + (CC).z - 4.0f * (CC).y; \
        const float lz_ = (NN).z + (SS).z + (CC).y + (CC).w - 4.0f * (CC).z; \
        const float lw_ = (NN).w + (SS).w + (CC).z + er_    - 4.0f * (CC).w; \
        (P).x = 2.0f * (CC).x - (P).x + (CI).x * lx_;                        \
        (P).y = 2.0f * (CC).y - (P).y + (CI).y * ly_;                        \
        (P).z = 2.0f * (CC).z - (P).z + (CI).z * lz_;                        \
        (P).w = 2.0f * (CC).w - (P).w + (CI).w * lw_;                        \
    }

#define INJECT(P) { if (sc == 0) (P).x += xi_; else if (sc == 1) (P).y += xi_; \
                    else if (sc == 2) (P).z += xi_; else (P).w += xi_; }

#define EMIT1(E, A0, A1, A2, A3, A4)                                         \
    { const int pk_ = (E); const int rr_ = (pk_ >> 2) & 7; const int c_ = pk_ & 3; \
      const float4 uu_ = (rr_ == 0) ? (A0) : ((rr_ == 1) ? (A1) :            \
                         ((rr_ == 2) ? (A2) : ((rr_ == 3) ? (A3) : (A4))));  \
      const float v_ = (c_ == 0) ? uu_.x : ((c_ == 1) ? uu_.y : ((c_ == 2) ? uu_.z : uu_.w));  \
      obuf[sidx_][pk_ >> 5] = v_; }

// One leapfrog step: newest currently in U*, previous in P*; after the step
// the newest is in P* (in-place). BS/BD: compile-time LDS ping-pong indices.
#define STEP(U0, U1, U2, U3, U4, P0, P1, P2, P3, P4, BS, BD, SIDX)           \
    {                                                                        \
        const int sidx_ = (SIDX);                                            \
        float4 nin_ = ZERO4, sin_ = ZERO4;                                   \
        if (!north_zero) nin_ = *(const float4*)&bnd[BS][rs - 1][1][xg];     \
        if (!south_zero) sin_ = *(const float4*)&bnd[BS][rs + 1][0][xg];     \
        LAPROW(P1, U0, U1, U2, c21);                                         \
        LAPROW(P2, U1, U2, U3, c22);                                         \
        LAPROW(P3, U2, U3, U4, c23);                                         \
        LAPROW(P0, nin_, U0, U1, c20);                                       \
        LAPROW(P4, U3, U4, sin_, c24);                                       \
        if (mine_src) {                                                      \
            const float xi_ = xs[sidx_];                                     \
            if (srr == 0)      INJECT(P0)                                    \
            else if (srr == 1) INJECT(P1)                                    \
            else if (srr == 2) INJECT(P2)                                    \
            else if (srr == 3) INJECT(P3)                                    \
            else               INJECT(P4)                                    \
        }                                                                    \
        *(float4*)&bnd[BD][rs][0][xg] = P0;                                  \
        *(float4*)&bnd[BD][rs][1][xg] = P4;                                  \
        if (cnt > 0) {                                                       \
            EMIT1(e0, P0, P1, P2, P3, P4);                                   \
            if (cnt > 1) { EMIT1(e1, P0, P1, P2, P3, P4);                    \
              if (cnt > 2) { EMIT1(e2, P0, P1, P2, P3, P4);                  \
                if (cnt > 3) { EMIT1(e3, P0, P1, P2, P3, P4);                \
                  if (cnt > 4) { EMIT1(e4, P0, P1, P2, P3, P4);              \
                    if (cnt > 5) { EMIT1(e5, P0, P1, P2, P3, P4); } } } } }  \
        }                                                                    \
    }

// c2 for one band row (loaded once; never changes). Rows >= RL get 0 ->
// those rows stay identically zero forever (they start 0 and c2=0).
#define LOADC2(I, C)                                                         \
    {                                                                        \
        const int r_ = r0 + (I);                                             \
        if (r_ < RL) {                                                       \
            const int gy_ = lo + r_;                                         \
            const float4 v_ = *(const float4*)&vp[gy_ * WW + xg];            \
            (C).x = v_.x * C2SCALE; (C).y = v_.y * C2SCALE;                  \
            (C).z = v_.z * C2SCALE; (C).w = v_.w * C2SCALE;                  \
            (C).x *= (C).x; (C).y *= (C).y; (C).z *= (C).z; (C).w *= (C).w;  \
        } else { (C) = ZERO4; }                                              \
    }

// write interior rows to global (inter-strip exchange payload)
#define SAVEROW(I, U, P)                                                     \
    {                                                                        \
        const int r_ = r0 + (I);                                             \
        const int gy_ = lo + r_;                                             \
        if (r_ < RL && gy_ >= y0 && gy_ < y0 + SHR) {                        \
            const size_t gi_ = bbase + (size_t)gy_ * WW + xg;                \
            *(float4*)&gcur[gi_]  = (U);                                     \
            *(float4*)&gprev[gi_] = (P);                                     \
        }                                                                    \
    }

// reload halo rows from neighbors' just-written interiors
#define RELOADROW(I, U, P)                                                   \
    {                                                                        \
        const int r_ = r0 + (I);                                             \
        const int gy_ = lo + r_;                                             \
        if (r_ < RL && (gy_ < y0 || gy_ >= y0 + SHR)) {                      \
            const size_t gi_ = bbase + (size_t)gy_ * WW + xg;                \
            (U) = *(const float4*)&gcur[gi_];                                \
            (P) = *(const float4*)&gprev[gi_];                               \
        }                                                                    \
    }

__global__ void __launch_bounds__(NTH) __attribute__((amdgpu_waves_per_eu(1, 4)))
wave_persist(const float* __restrict__ x, const float* __restrict__ vp,
             const int* __restrict__ src_y, const int* __restrict__ src_x,
             const int* __restrict__ rec_y, const int* __restrict__ rec_x,
             float* __restrict__ gcur, float* __restrict__ gprev,
             float* __restrict__ out, int NT, int B, int NR)
{
    cg::grid_group gg = cg::this_grid();

    __shared__ float bnd[2][NSLOT][2][WW];   // 32 KB ping-pong boundary rows
    __shared__ float obuf[KT][NRMAX];        // 8 KB receiver samples
    __shared__ int   rec_s[NRMAX];
    __shared__ float xs[KT];

    const int strip = blockIdx.x;
    const int bb    = blockIdx.y;
    const int y0    = strip * SHR;
    const int lo    = max(0, y0 - KT);
    const int hi    = min(HH, y0 + SHR + KT);
    const int RL    = hi - lo;               // region rows (<= 40)

    const int tid  = threadIdx.x;
    const int lane = tid & 63;
    const int rs   = tid >> 6;               // wave id == row slot
    const int xg   = lane * 4;
    const int r0   = rs * RPT;
    const int gy0  = lo + r0;

    const size_t bbase = (size_t)bb * HH * WW;

    // ---- one-time setup ----
    if (tid < NR) rec_s[tid] = (rec_y[tid] << 8) | rec_x[tid];

    float4 u0 = ZERO4, u1 = ZERO4, u2 = ZERO4, u3 = ZERO4, u4 = ZERO4;
    float4 p0 = ZERO4, p1 = ZERO4, p2 = ZERO4, p3 = ZERO4, p4 = ZERO4;
    float4 c20, c21, c22, c23, c24;
    LOADC2(0, c20); LOADC2(1, c21); LOADC2(2, c22); LOADC2(3, c23); LOADC2(4, c24);

    const int sy = src_y[bb];
    const int sx = src_x[bb];
    const int srr = sy - gy0;                        // 0..4 if mine
    const bool mine_src = (sy >= lo) && (sy < hi) &&
                          (srr >= 0) && (srr < RPT) && ((sx >> 2) == lane);
    const int sc = sx & 3;

    __syncthreads();                                 // fence rec_s

    // receiver ownership: <=6 static slots per thread (LDS broadcast scan)
    int e0 = 0, e1 = 0, e2 = 0, e3 = 0, e4 = 0, e5 = 0, cnt = 0;
    for (int k = 0; k < NR; ++k) {
        const int rc = rec_s[k];
        const int ry = rc >> 8;
        if (ry >= y0 && ry < y0 + SHR) {
            const int rr = ry - gy0;
            if (rr >= 0 && rr < RPT) {
                const int rx = rc & 255;
                if ((rx >> 2) == lane) {
                    const int pk = (k << 5) | (rr << 2) | (rx & 3);
                    if (cnt == 0) e0 = pk; else if (cnt == 1) e1 = pk;
                    else if (cnt == 2) e2 = pk; else if (cnt == 3) e3 = pk;
                    else if (cnt == 4) e4 = pk; else e5 = pk;
                    ++cnt;
                }
            }
        }
    }

    const bool north_zero = (rs == 0);
    const bool south_zero = (rs == NSLOT - 1) || (gy0 + RPT - 1 == HH - 1);

    // ---- chunk loop: KT steps, then halo exchange through global ----
    for (int t0 = 0; t0 < NT; t0 += KT) {
        const int ns = (NT - t0 < KT) ? (NT - t0) : KT;   // 16 or 8 (even)

        if (tid < ns) xs[tid] = x[(t0 + tid) * B + bb];
        *(float4*)&bnd[0][rs][0][xg] = u0;
        *(float4*)&bnd[0][rs][1][xg] = u4;
        __syncthreads();

        #pragma unroll 1
        for (int s = 0; s < ns; s += 2) {
            STEP(u0, u1, u2, u3, u4, p0, p1, p2, p3, p4, 0, 1, s);     // newest -> p*
            __syncthreads();
            STEP(p0, p1, p2, p3, p4, u0, u1, u2, u3, u4, 1, 0, s + 1); // newest -> u*
            __syncthreads();
        }
        // after an even number of steps: u* = newest, p* = one-older.

        // flush receiver samples for this chunk
        for (int p = tid; p < KT * NRMAX; p += NTH) {
            const int s = p >> 7;          // p / 128
            const int k = p & 127;
            if (s < ns && k < NR) {
                const int rc = rec_s[k];
                const int ry = rc >> 8;
                if (ry >= y0 && ry < y0 + SHR) {
                    out[(size_t)(t0 + s) * B * NR + (size_t)bb * NR + k] = obuf[s][k];
                }
            }
        }

        if (t0 + KT < NT) {
            // inter-strip halo exchange: write my interior, sync, read halo
            SAVEROW(0, u0, p0); SAVEROW(1, u1, p1); SAVEROW(2, u2, p2);
            SAVEROW(3, u3, p3); SAVEROW(4, u4, p4);
            gg.sync();
            RELOADROW(0, u0, p0); RELOADROW(1, u1, p1); RELOADROW(2, u2, p2);
            RELOADROW(3, u3, p3); RELOADROW(4, u4, p4);
        }
    }
}

extern "C" void kernel_launch(void* const* d_in, const int* in_sizes, int n_in,
                              void* d_out, int out_size, void* d_ws, size_t ws_size,
                              hipStream_t stream) {
    const float* x     = (const float*)d_in[0];
    const float* vp    = (const float*)d_in[1];
    const int* src_y   = (const int*)d_in[2];
    const int* src_x   = (const int*)d_in[3];
    const int* rec_y   = (const int*)d_in[4];
    const int* rec_x   = (const int*)d_in[5];

    int B  = in_sizes[2];
    int NR = in_sizes[4];
    int NT = in_sizes[0] / B;

    float* gcur  = (float*)d_ws;
    float* gprev = gcur + (size_t)B * HH * WW;
    float* outp  = (float*)d_out;

    void* args[] = { (void*)&x, (void*)&vp, (void*)&src_y, (void*)&src_x,
                     (void*)&rec_y, (void*)&rec_x, (void*)&gcur, (void*)&gprev,
                     (void*)&outp, (void*)&NT, (void*)&B, (void*)&NR };

    hipLaunchCooperativeKernel((const void*)wave_persist,
                               dim3(NSTRIP, B), dim3(NTH), args, 0, stream);
}

// Round 11
// 717.862 us; speedup vs baseline: 4.3258x; 4.3258x over previous
//
#include <hip/hip_runtime.h>
#include <hip/hip_cooperative_groups.h>

namespace cg = cooperative_groups;

// 2D acoustic FDTD, persistent cooperative kernel with temporal blocking.
// One launch, NT=600 steps. 16 strips (16 interior rows) x B blocks = 32
// blocks of 1024 threads (16 waves = 4/SIMD). Each wave owns 3 consecutive
// rows in NAMED float4 registers; band top/bottom rows exchange via LDS
// ping-pong (1 barrier/step); strips exchange halo via global + grid.sync
// every KT=16 steps. Lateral neighbors via DPP (bound_ctrl = edge zeros).
// R11 == R10 resubmit (GPU acquisition timeout; kernel never ran).
// R10 vs R9: R9's RPT=5 spilled (VGPR 68 < need ~100; WRITE 251MB scratch
// signature). R10 shrinks per-thread state to 9 float4 (36 regs, under the
// proven no-spill budget of R6's 12 float4) while still doubling CU count
// vs R6 (32 blocks) and cutting per-SIMD row work 16 -> 12.

#define HH 256
#define WW 256
#define KT 16                 // time steps per chunk == halo rows
#define SHR 16                // strip interior height
#define NSTRIP (HH / SHR)     // 16
#define NSLOT 16              // row-slots (= waves) per block
#define RPT 3                 // rows per thread; 16*3=48 == 16+2*16 region
#define NTH 1024
#define C2SCALE 1.0e-4f       // DT/DX
#define NRMAX 128

__device__ __forceinline__ float dpp_west(float v) {
    // lane i <- lane i-1 ; lane 0 <- 0   (wave_shr:1, bound_ctrl:1)
    return __int_as_float(__builtin_amdgcn_mov_dpp(__float_as_int(v), 0x138, 0xf, 0xf, true));
}
__device__ __forceinline__ float dpp_east(float v) {
    // lane i <- lane i+1 ; lane 63 <- 0  (wave_shl:1, bound_ctrl:1)
    return __int_as_float(__builtin_amdgcn_mov_dpp(__float_as_int(v), 0x130, 0xf, 0xf, true));
}

#define ZERO4 make_float4(0.f, 0.f, 0.f, 0.f)

// P = 2*C - P + CI * lap(N, C, S)     (in-place leapfrog, P aliases u_{t-1})
#define LAPROW(P, NN, CC, SS, CI)                                            \
    {                                                                        \
        const float wl_ = dpp_west((CC).w);                                  \
        const float er_ = dpp_east((CC).x);                                  \
        const float lx_ = (NN).x + (SS).x + wl_    + (CC).y - 4.0f * (CC).x; \
        const float ly_ = (NN).y + (SS).y + (CC).x + (CC).z - 4.0f * (CC).y; \
        const float lz_ = (NN).z + (SS).z + (CC).y + (CC).w - 4.0f * (CC).z; \
        const float lw_ = (NN).w + (SS).w + (CC).z + er_    - 4.0f * (CC).w; \
        (P).x = 2.0f * (CC).x - (P).x + (CI).x * lx_;                        \
        (P).y = 2.0f * (CC).y - (P).y + (CI).y * ly_;                        \
        (P).z = 2.0f * (CC).z - (P).z + (CI).z * lz_;                        \
        (P).w = 2.0f * (CC).w - (P).w + (CI).w * lw_;                        \
    }

#define INJECT(P) { if (sc == 0) (P).x += xi_; else if (sc == 1) (P).y += xi_; \
                    else if (sc == 2) (P).z += xi_; else (P).w += xi_; }

#define EMIT1(E, A0, A1, A2)                                                 \
    { const int pk_ = (E); const int rr_ = (pk_ >> 2) & 7; const int c_ = pk_ & 3; \
      const float4 uu_ = (rr_ == 0) ? (A0) : ((rr_ == 1) ? (A1) : (A2));     \
      const float v_ = (c_ == 0) ? uu_.x : ((c_ == 1) ? uu_.y : ((c_ == 2) ? uu_.z : uu_.w));  \
      obuf[sidx_][pk_ >> 5] = v_; }

// One leapfrog step: newest currently in U*, previous in P*; after the step
// the newest is in P* (in-place). BS/BD: compile-time LDS ping-pong indices.
#define STEP(U0, U1, U2, P0, P1, P2, BS, BD, SIDX)                           \
    {                                                                        \
        const int sidx_ = (SIDX);                                            \
        float4 nin_ = ZERO4, sin_ = ZERO4;                                   \
        if (!north_zero) nin_ = *(const float4*)&bnd[BS][rs - 1][1][xg];     \
        if (!south_zero) sin_ = *(const float4*)&bnd[BS][rs + 1][0][xg];     \
        LAPROW(P1, U0, U1, U2, c21);                                         \
        LAPROW(P0, nin_, U0, U1, c20);                                       \
        LAPROW(P2, U1, U2, sin_, c22);                                       \
        if (mine_src) {                                                      \
            const float xi_ = xs[sidx_];                                     \
            if (srr == 0)      INJECT(P0)                                    \
            else if (srr == 1) INJECT(P1)                                    \
            else               INJECT(P2)                                    \
        }                                                                    \
        *(float4*)&bnd[BD][rs][0][xg] = P0;                                  \
        *(float4*)&bnd[BD][rs][1][xg] = P2;                                  \
        if (cnt > 0) {                                                       \
            EMIT1(e0, P0, P1, P2);                                           \
            if (cnt > 1) { EMIT1(e1, P0, P1, P2);                            \
              if (cnt > 2) { EMIT1(e2, P0, P1, P2);                          \
                if (cnt > 3) { EMIT1(e3, P0, P1, P2);                        \
                  if (cnt > 4) { EMIT1(e4, P0, P1, P2);                      \
                    if (cnt > 5) { EMIT1(e5, P0, P1, P2); } } } } }          \
        }                                                                    \
    }

// c2 for one band row (loaded once; never changes). Rows >= RL get 0 ->
// those rows stay identically zero forever (they start 0 and c2=0).
#define LOADC2(I, C)                                                         \
    {                                                                        \
        const int r_ = r0 + (I);                                             \
        if (r_ < RL) {                                                       \
            const int gy_ = lo + r_;                                         \
            const float4 v_ = *(const float4*)&vp[gy_ * WW + xg];            \
            (C).x = v_.x * C2SCALE; (C).y = v_.y * C2SCALE;                  \
            (C).z = v_.z * C2SCALE; (C).w = v_.w * C2SCALE;                  \
            (C).x *= (C).x; (C).y *= (C).y; (C).z *= (C).z; (C).w *= (C).w;  \
        } else { (C) = ZERO4; }                                              \
    }

// write interior rows to global (inter-strip exchange payload)
#define SAVEROW(I, U, P)                                                     \
    {                                                                        \
        const int r_ = r0 + (I);                                             \
        const int gy_ = lo + r_;                                             \
        if (r_ < RL && gy_ >= y0 && gy_ < y0 + SHR) {                        \
            const size_t gi_ = bbase + (size_t)gy_ * WW + xg;                \
            *(float4*)&gcur[gi_]  = (U);                                     \
            *(float4*)&gprev[gi_] = (P);                                     \
        }                                                                    \
    }

// reload halo rows from neighbors' just-written interiors
#define RELOADROW(I, U, P)                                                   \
    {                                                                        \
        const int r_ = r0 + (I);                                             \
        const int gy_ = lo + r_;                                             \
        if (r_ < RL && (gy_ < y0 || gy_ >= y0 + SHR)) {                      \
            const size_t gi_ = bbase + (size_t)gy_ * WW + xg;                \
            (U) = *(const float4*)&gcur[gi_];                                \
            (P) = *(const float4*)&gprev[gi_];                               \
        }                                                                    \
    }

__global__ void __launch_bounds__(NTH) __attribute__((amdgpu_waves_per_eu(1, 4)))
wave_persist(const float* __restrict__ x, const float* __restrict__ vp,
             const int* __restrict__ src_y, const int* __restrict__ src_x,
             const int* __restrict__ rec_y, const int* __restrict__ rec_x,
             float* __restrict__ gcur, float* __restrict__ gprev,
             float* __restrict__ out, int NT, int B, int NR)
{
    cg::grid_group gg = cg::this_grid();

    __shared__ float bnd[2][NSLOT][2][WW];   // 64 KB ping-pong boundary rows
    __shared__ float obuf[KT][NRMAX];        // 8 KB receiver samples
    __shared__ int   rec_s[NRMAX];
    __shared__ float xs[KT];

    const int strip = blockIdx.x;
    const int bb    = blockIdx.y;
    const int y0    = strip * SHR;
    const int lo    = max(0, y0 - KT);
    const int hi    = min(HH, y0 + SHR + KT);
    const int RL    = hi - lo;               // region rows (48 interior, 32 edge)

    const int tid  = threadIdx.x;
    const int lane = tid & 63;
    const int rs   = tid >> 6;               // wave id == row slot
    const int xg   = lane * 4;
    const int r0   = rs * RPT;
    const int gy0  = lo + r0;

    const size_t bbase = (size_t)bb * HH * WW;

    // ---- one-time setup ----
    if (tid < NR) rec_s[tid] = (rec_y[tid] << 8) | rec_x[tid];

    float4 u0 = ZERO4, u1 = ZERO4, u2 = ZERO4;
    float4 p0 = ZERO4, p1 = ZERO4, p2 = ZERO4;
    float4 c20, c21, c22;
    LOADC2(0, c20); LOADC2(1, c21); LOADC2(2, c22);

    const int sy = src_y[bb];
    const int sx = src_x[bb];
    const int srr = sy - gy0;                        // 0..2 if mine
    const bool mine_src = (sy >= lo) && (sy < hi) &&
                          (srr >= 0) && (srr < RPT) && ((sx >> 2) == lane);
    const int sc = sx & 3;

    __syncthreads();                                 // fence rec_s

    // receiver ownership: <=6 static slots per thread (LDS broadcast scan)
    int e0 = 0, e1 = 0, e2 = 0, e3 = 0, e4 = 0, e5 = 0, cnt = 0;
    for (int k = 0; k < NR; ++k) {
        const int rc = rec_s[k];
        const int ry = rc >> 8;
        if (ry >= y0 && ry < y0 + SHR) {
            const int rr = ry - gy0;
            if (rr >= 0 && rr < RPT) {
                const int rx = rc & 255;
                if ((rx >> 2) == lane) {
                    const int pk = (k << 5) | (rr << 2) | (rx & 3);
                    if (cnt == 0) e0 = pk; else if (cnt == 1) e1 = pk;
                    else if (cnt == 2) e2 = pk; else if (cnt == 3) e3 = pk;
                    else if (cnt == 4) e4 = pk; else e5 = pk;
                    ++cnt;
                }
            }
        }
    }

    const bool north_zero = (rs == 0);
    const bool south_zero = (rs == NSLOT - 1) || (gy0 + RPT - 1 == HH - 1);

    // ---- chunk loop: KT steps, then halo exchange through global ----
    for (int t0 = 0; t0 < NT; t0 += KT) {
        const int ns = (NT - t0 < KT) ? (NT - t0) : KT;   // 16 or 8 (even)

        if (tid < ns) xs[tid] = x[(t0 + tid) * B + bb];
        *(float4*)&bnd[0][rs][0][xg] = u0;
        *(float4*)&bnd[0][rs][1][xg] = u2;
        __syncthreads();

        #pragma unroll 1
        for (int s = 0; s < ns; s += 2) {
            STEP(u0, u1, u2, p0, p1, p2, 0, 1, s);       // newest -> p*
            __syncthreads();
            STEP(p0, p1, p2, u0, u1, u2, 1, 0, s + 1);   // newest -> u*
            __syncthreads();
        }
        // after an even number of steps: u* = newest, p* = one-older.

        // flush receiver samples for this chunk
        for (int p = tid; p < KT * NRMAX; p += NTH) {
            const int s = p >> 7;          // p / 128
            const int k = p & 127;
            if (s < ns && k < NR) {
                const int rc = rec_s[k];
                const int ry = rc >> 8;
                if (ry >= y0 && ry < y0 + SHR) {
                    out[(size_t)(t0 + s) * B * NR + (size_t)bb * NR + k] = obuf[s][k];
                }
            }
        }

        if (t0 + KT < NT) {
            // inter-strip halo exchange: write my interior, sync, read halo
            SAVEROW(0, u0, p0); SAVEROW(1, u1, p1); SAVEROW(2, u2, p2);
            gg.sync();
            RELOADROW(0, u0, p0); RELOADROW(1, u1, p1); RELOADROW(2, u2, p2);
        }
    }
}

extern "C" void kernel_launch(void* const* d_in, const int* in_sizes, int n_in,
                              void* d_out, int out_size, void* d_ws, size_t ws_size,
                              hipStream_t stream) {
    const float* x     = (const float*)d_in[0];
    const float* vp    = (const float*)d_in[1];
    const int* src_y   = (const int*)d_in[2];
    const int* src_x   = (const int*)d_in[3];
    const int* rec_y   = (const int*)d_in[4];
    const int* rec_x   = (const int*)d_in[5];

    int B  = in_sizes[2];
    int NR = in_sizes[4];
    int NT = in_sizes[0] / B;

    float* gcur  = (float*)d_ws;
    float* gprev = gcur + (size_t)B * HH * WW;
    float* outp  = (float*)d_out;

    void* args[] = { (void*)&x, (void*)&vp, (void*)&src_y, (void*)&src_x,
                     (void*)&rec_y, (void*)&rec_x, (void*)&gcur, (void*)&gprev,
                     (void*)&outp, (void*)&NT, (void*)&B, (void*)&NR };

    hipLaunchCooperativeKernel((const void*)wave_persist,
                               dim3(NSTRIP, B), dim3(NTH), args, 0, stream);
}